// Round 15
// baseline (118.478 us; speedup 1.0000x reference)
//
#include <hip/hip_runtime.h>
#include <hip/hip_bf16.h>
#include <math.h>

#define NB 8
#define LL 8192
#define DD 64
#define NS 11
#define NR 4
#define NC 512        // chunks
#define LC (LL/NC)    // 16 positions per chunk
#define CONV_LT 64
#define KW 63
#define PJ 64         // proj tile = 4 chunks
#define NBKT 16       // BN atomic buckets
#define US 68         // LDS row stride for ul/del (16-bank shift per row)

__device__ __forceinline__ float sigmoidf_(float v){ return 1.f/(1.f+__expf(-v)); }

// ---------------- K0: zero the BN accumulator ----------------
__global__ void k_zero(float* __restrict__ p){
  p[blockIdx.x*256 + threadIdx.x] = 0.f;
}

// ---------------- K1: depthwise conv (k=63, pad 31) + bucketed BN partial sums ------
// register-window inner loop: dense 16x16 FMA block, no predication
__global__ __launch_bounds__(256,4) void k_conv(const float* __restrict__ x,
                                              const float* __restrict__ w,
                                              float* __restrict__ xc,
                                              float* __restrict__ bn_acc){
  const int b  = blockIdx.x / (LL/CONV_LT);
  const int lt = blockIdx.x % (LL/CONV_LT);
  const int l0 = lt*CONV_LT;
  __shared__ float xt[(CONV_LT+62)*DD];   // 32.2 KB
  __shared__ float rs[256], rq[256];
  const int t = threadIdx.x;
  for (int i=t; i<(CONV_LT+62)*DD; i+=256){
    int lrel = i/DD, d = i%DD;
    int lg = l0 - 31 + lrel;
    xt[i] = (lg>=0 && lg<LL) ? x[((size_t)b*LL+lg)*DD + d] : 0.f;
  }
  __syncthreads();
  const int d = t & 63;
  const int base = (t >> 6) * 16;
  float acc[16];
  #pragma unroll
  for (int j=0;j<16;j++) acc[j]=0.f;
  #pragma unroll 1
  for (int kb=0; kb<4; ++kb){
    float wv[16];
    #pragma unroll
    for (int kk=0;kk<16;kk++){
      int k = kb*16+kk;
      wv[kk] = (k<KW) ? w[d*KW+k] : 0.f;
    }
    float xw[31];
    #pragma unroll
    for (int i=0;i<31;i++) xw[i] = xt[(base+kb*16+i)*DD + d];
    #pragma unroll
    for (int j=0;j<16;j++){
      #pragma unroll
      for (int kk=0;kk<16;kk++){
        acc[j] = fmaf(wv[kk], xw[j+kk], acc[j]);
      }
    }
  }
  float lsum=0.f, lsq=0.f;
  #pragma unroll
  for (int j=0;j<16;j++){
    xc[((size_t)b*LL + l0+base+j)*DD + d] = acc[j];
    lsum += acc[j]; lsq = fmaf(acc[j],acc[j],lsq);
  }
  rs[t]=lsum; rq[t]=lsq;
  __syncthreads();
  if (t<64){
    float s = rs[t]+rs[t+64]+rs[t+128]+rs[t+192];
    float q = rq[t]+rq[t+64]+rq[t+128]+rq[t+192];
    const int bkt = (blockIdx.x & (NBKT-1))*128;
    atomicAdd(&bn_acc[bkt+t],    s);
    atomicAdd(&bn_acc[bkt+64+t], q);
  }
}

// ---------------- K2: BN+SiLU ; vectorized x_proj ; dt proj -> duo ; fused local scan
__global__ __launch_bounds__(256,3) void k_proj(const float* __restrict__ xc,
                                              const float* __restrict__ bn_acc,
                                              const float* __restrict__ gamma,
                                              const float* __restrict__ beta,
                                              const float* __restrict__ xpw,
                                              const float* __restrict__ dtw,
                                              const float* __restrict__ dtb,
                                              const float* __restrict__ Alog,
                                              float* __restrict__ duo,
                                              float* __restrict__ bc,
                                              float* __restrict__ chunkst){
  const int b  = blockIdx.x / (LL/PJ);
  const int lt = blockIdx.x % (LL/PJ);
  const int l0 = lt*PJ;
  __shared__ float ul[PJ*US];          // 17.4 KB
  __shared__ float del[PJ*US];         // 17.4 KB
  __shared__ float bcl[PJ][24];        // 6 KB (slots 11,23 unused)
  __shared__ float wsh2[26*US];        // 7.1 KB, c-major rows (contiguous dd)
  __shared__ float xd[PJ*NR];          // 1 KB
  __shared__ float dtwsh[64*NR];       // 1 KB
  const int t = threadIdx.x;
  for (int i=t; i<26*64; i+=256){ int c=i>>6, dd=i&63; wsh2[c*US+dd] = xpw[i]; }
  dtwsh[t] = dtw[t];
  const int d = t & 63, lq = t >> 6;
  float msum = 0.f, qsum = 0.f;
  #pragma unroll
  for (int k=0;k<NBKT;k++){
    msum += bn_acc[k*128 + d];
    qsum += bn_acc[k*128 + 64 + d];
  }
  const float inv_n = 1.f/((float)NB*(float)LL);
  float mean = msum*inv_n;
  float var  = qsum*inv_n - mean*mean;
  float sc = gamma[d] * rsqrtf(var + 1e-5f);
  float sh = beta[d] - mean*sc;
  #pragma unroll
  for (int j=0;j<PJ/4;j++){
    int lr = lq + 4*j;
    float v = xc[((size_t)b*LL + l0+lr)*DD + d];
    v = fmaf(v, sc, sh);
    float uu = v * sigmoidf_(v);
    ul[lr*US+d] = uu;
  }
  __syncthreads();
  // x_proj matvec: 2 cols x 4 pos x 4-dd float4 blocking; unroll capped to avoid spill
  {
    const int cp  = t & 15;            // c-pair 0..12 active
    const int lrb = t >> 4;            // position group 0..15
    if (cp < 13){
      float acc0[4] = {0.f,0.f,0.f,0.f};
      float acc1[4] = {0.f,0.f,0.f,0.f};
      #pragma unroll 2
      for (int dd4=0; dd4<16; ++dd4){
        float4 w0 = *reinterpret_cast<const float4*>(&wsh2[(2*cp  )*US + dd4*4]);
        float4 w1 = *reinterpret_cast<const float4*>(&wsh2[(2*cp+1)*US + dd4*4]);
        #pragma unroll
        for (int p=0;p<4;p++){
          float4 uv = *reinterpret_cast<const float4*>(&ul[(lrb*4+p)*US + dd4*4]);
          acc0[p] = fmaf(w0.x,uv.x, fmaf(w0.y,uv.y, fmaf(w0.z,uv.z, fmaf(w0.w,uv.w, acc0[p]))));
          acc1[p] = fmaf(w1.x,uv.x, fmaf(w1.y,uv.y, fmaf(w1.z,uv.z, fmaf(w1.w,uv.w, acc1[p]))));
        }
      }
      #pragma unroll
      for (int cc=0; cc<2; ++cc){
        int c = 2*cp+cc;
        #pragma unroll
        for (int p=0;p<4;p++){
          int lr = lrb*4+p;
          float v = cc ? acc1[p] : acc0[p];
          if (c < NR) xd[lr*NR+c] = v;
          else {
            int pos = c - NR;                       // B:0..10  C:11..21
            int slot = (pos < NS) ? pos : pos+1;    // pad slots 11 and 23
            bcl[lr][slot] = v;
            bc[((size_t)b*LL + l0+lr)*24 + slot] = v;
          }
        }
      }
    }
  }
  __syncthreads();
  // dt proj + softplus -> del (LDS) + duo (global)
  {
    float bias = dtb[d];
    #pragma unroll
    for (int j=0;j<PJ/4;j++){
      int lr = lq + 4*j;
      float s = bias;
      #pragma unroll
      for (int r=0;r<NR;r++) s = fmaf(dtwsh[d*NR+r], xd[lr*NR+r], s);
      float sp = fmaxf(s,0.f) + log1pf(expf(-fabsf(s)));
      del[lr*US+d] = sp;
      float2 st; st.x = sp; st.y = ul[lr*US+d];
      *reinterpret_cast<float2*>(duo + (((size_t)b*LL + l0+lr)*DD + d)*2) = st;
    }
  }
  __syncthreads();
  // fused chunk-local scan: wave wv = chunk lt*4+wv, lane = d
  {
    const int wv = lq;                 // wave id 0..3
    const int task = b*NC + lt*4 + wv;
    float a[NS];
    #pragma unroll
    for (int n=0;n<NS;n++) a[n] = -expf(Alog[d*NS+n]);
    float h[12];
    #pragma unroll
    for (int n=0;n<12;n++) h[n]=0.f;
    float dsum=0.f;
    #pragma unroll 4
    for (int l=0;l<LC;++l){
      int lr = wv*LC + l;
      float de = del[lr*US+d];
      float du = de*ul[lr*US+d];
      dsum += de;
      #pragma unroll
      for (int n=0;n<NS;n++){
        float dA = __expf(a[n]*de);
        h[n] = fmaf(dA, h[n], du*bcl[lr][n]);
      }
    }
    h[11] = dsum;
    float4* o = reinterpret_cast<float4*>(chunkst + ((size_t)task*64 + d)*12);
    o[0] = *reinterpret_cast<float4*>(&h[0]);
    o[1] = *reinterpret_cast<float4*>(&h[4]);
    o[2] = *reinterpret_cast<float4*>(&h[8]);
  }
}

// ---------------- K4: cross-chunk propagation — one wave per (b,d) -----------------
__global__ __launch_bounds__(64) void k_scanMid(const float* __restrict__ chunkst,
                                                const float* __restrict__ Alog,
                                                float* __restrict__ hin){
  const int wid  = blockIdx.x;                        // 0..511 = b*64+d
  const int lane = threadIdx.x & 63;
  const int b = wid >> 6, d = wid & 63;
  const int c0 = lane*8;
  const size_t recbase = (((size_t)b*NC + c0)*64 + d)*12;   // + j*768
  float aAll[NS];
  #pragma unroll
  for (int n=0;n<NS;n++) aAll[n] = -expf(Alog[d*NS+n]);
  float Aa[NS], Bb[NS];
  #pragma unroll
  for (int n=0;n<NS;n++){ Aa[n]=1.f; Bb[n]=0.f; }
  #pragma unroll
  for (int j=0;j<8;j++){
    float rec[12];
    const float4* q = reinterpret_cast<const float4*>(chunkst + recbase + (size_t)j*768);
    *reinterpret_cast<float4*>(&rec[0]) = q[0];
    *reinterpret_cast<float4*>(&rec[4]) = q[1];
    *reinterpret_cast<float4*>(&rec[8]) = q[2];
    float ds = rec[11];
    #pragma unroll
    for (int n=0;n<NS;n++){
      float dA = __expf(aAll[n]*ds);
      Bb[n] = fmaf(dA, Bb[n], rec[n]);
      Aa[n] *= dA;
    }
  }
  #pragma unroll
  for (int n=0;n<NS;n++){
    float A = Aa[n], Bv = Bb[n];
    #pragma unroll
    for (int off=1; off<64; off<<=1){
      float Ap=__shfl_up(A,off,64), Bp=__shfl_up(Bv,off,64);
      if (lane>=off){ Bv = fmaf(A,Bp,Bv); A*=Ap; }
    }
    float hs = __shfl_up(Bv,1,64);
    Bb[n] = (lane==0) ? 0.f : hs;     // h at chunk c0 (global h0=0)
  }
  #pragma unroll
  for (int j=0;j<8;j++){
    float rec[12];
    const float4* q = reinterpret_cast<const float4*>(chunkst + recbase + (size_t)j*768);
    *reinterpret_cast<float4*>(&rec[0]) = q[0];
    *reinterpret_cast<float4*>(&rec[4]) = q[1];
    *reinterpret_cast<float4*>(&rec[8]) = q[2];
    float ds = rec[11];
    float outv[12];
    #pragma unroll
    for (int n=0;n<NS;n++){
      outv[n] = Bb[n];
      float dA = __expf(aAll[n]*ds);
      Bb[n] = fmaf(dA, Bb[n], rec[n]);
    }
    outv[11] = 0.f;
    float4* o = reinterpret_cast<float4*>(hin + recbase + (size_t)j*768);
    o[0] = *reinterpret_cast<float4*>(&outv[0]);
    o[1] = *reinterpret_cast<float4*>(&outv[4]);
    o[2] = *reinterpret_cast<float4*>(&outv[8]);
  }
}

// ---------------- K5: replay scan with h_in, y, RMSNorm over D, SiLU gating -------
__global__ __launch_bounds__(256,4) void k_scanB(const float* __restrict__ duo,
                                               const float* __restrict__ bc,
                                               const float* __restrict__ Alog,
                                               const float* __restrict__ hin,
                                               const float* __restrict__ Dsv,
                                               const float* __restrict__ rmss,
                                               const float* __restrict__ x,
                                               float* __restrict__ out){
  const int task = blockIdx.x*4 + (threadIdx.x>>6);
  const int d = threadIdx.x & 63;
  const int b = task / NC, c = task % NC;
  float a[NS], h[12];
  #pragma unroll
  for (int n=0;n<NS;n++) a[n] = -expf(Alog[d*NS+n]);
  {
    const float4* q = reinterpret_cast<const float4*>(hin + ((size_t)task*64 + d)*12);
    *reinterpret_cast<float4*>(&h[0]) = q[0];
    *reinterpret_cast<float4*>(&h[4]) = q[1];
    *reinterpret_cast<float4*>(&h[8]) = q[2];
  }
  const float Dd = Dsv[d];
  const float rsc = rmss[d];
  const int l0 = c*LC;
  #pragma unroll 2
  for (int l=l0; l<l0+LC; ++l){
    size_t p = (size_t)b*LL + l;
    float2 du2 = *reinterpret_cast<const float2*>(duo + (p*DD+d)*2);
    float de = du2.x, uu = du2.y;
    float du = de*uu;
    float bca[24];
    const float4* q = reinterpret_cast<const float4*>(bc + p*24);
    *reinterpret_cast<float4*>(&bca[0])  = q[0];
    *reinterpret_cast<float4*>(&bca[4])  = q[1];
    *reinterpret_cast<float4*>(&bca[8])  = q[2];
    *reinterpret_cast<float4*>(&bca[12]) = q[3];
    *reinterpret_cast<float4*>(&bca[16]) = q[4];
    *reinterpret_cast<float4*>(&bca[20]) = q[5];
    float y = Dd*uu;
    #pragma unroll
    for (int n=0;n<NS;n++){
      float dA = __expf(a[n]*de);
      h[n] = fmaf(dA, h[n], du*bca[n]);
      y = fmaf(h[n], bca[12+n], y);
    }
    float ss = y*y;
    #pragma unroll
    for (int m=1;m<64;m<<=1) ss += __shfl_xor(ss, m, 64);
    float yn = rsc * rsqrtf(ss*(1.f/64.f) + 1e-5f) * y;
    float z = x[p*DD+d];
    out[p*DD+d] = yn * (z * sigmoidf_(z));
  }
}

extern "C" void kernel_launch(void* const* d_in, const int* in_sizes, int n_in,
                              void* d_out, int out_size, void* d_ws, size_t ws_size,
                              hipStream_t stream) {
  const float* x     = (const float*)d_in[0];
  const float* w     = (const float*)d_in[1];
  const float* gamma = (const float*)d_in[2];
  const float* beta  = (const float*)d_in[3];
  const float* xpw   = (const float*)d_in[4];
  const float* dtw   = (const float*)d_in[5];
  const float* dtb   = (const float*)d_in[6];
  const float* Alog  = (const float*)d_in[7];
  const float* Dsv   = (const float*)d_in[8];
  const float* rmss  = (const float*)d_in[9];
  float* out = (float*)d_out;

  float* f = (float*)d_ws;
  const size_t n_xld = (size_t)NB*LL*DD;       // 4,194,304
  float* xc      = f;                          // conv out
  float* duo     = xc + n_xld;                 // (b,l,d,2): delta, u
  float* bc      = duo + 2*n_xld;              // (b,l,24): B[0..10],pad,C[0..10],pad
  float* chunkst = bc + (size_t)NB*LL*24;      // (b,c,d,12): h_end[0..10], dsum
  float* hin     = chunkst + (size_t)NB*NC*64*12;  // (b,c,d,12): h_in[0..10], pad
  float* bn_acc  = hin + (size_t)NB*NC*64*12;      // 16 buckets x 128

  k_zero   <<<NBKT*128/256, 256, 0, stream>>>(bn_acc);
  k_conv   <<<NB*(LL/CONV_LT), 256, 0, stream>>>(x, w, xc, bn_acc);
  k_proj   <<<NB*(LL/PJ), 256, 0, stream>>>(xc, bn_acc, gamma, beta, xpw, dtw, dtb, Alog, duo, bc, chunkst);
  k_scanMid<<<NB*DD, 64, 0, stream>>>(chunkst, Alog, hin);
  k_scanB  <<<(NB*NC)/4, 256, 0, stream>>>(duo, bc, Alog, hin, Dsv, rmss, x, out);
}

// Round 16
// 95.104 us; speedup vs baseline: 1.2458x; 1.2458x over previous
//
#include <hip/hip_runtime.h>
#include <hip/hip_bf16.h>
#include <math.h>

#define NB 8
#define LL 8192
#define DD 64
#define NS 11
#define NR 4
#define NC 512        // chunks
#define LC (LL/NC)    // 16 positions per chunk
#define CONV_LT 64
#define KW 63
#define PJ 64         // proj tile = 4 chunks
#define NBKT 16       // BN atomic buckets
#define US 68         // LDS row stride for ul (16-bank shift per row, 16B aligned)
#define WS 72         // LDS row stride for wsh2 (2-way max on b128 reads)

__device__ __forceinline__ float sigmoidf_(float v){ return 1.f/(1.f+__expf(-v)); }

// ---------------- K0: zero the BN accumulator ----------------
__global__ void k_zero(float* __restrict__ p){
  p[blockIdx.x*256 + threadIdx.x] = 0.f;
}

// ---------------- K1: depthwise conv (k=63, pad 31) + bucketed BN partial sums ------
__global__ __launch_bounds__(256,4) void k_conv(const float* __restrict__ x,
                                              const float* __restrict__ w,
                                              float* __restrict__ xc,
                                              float* __restrict__ bn_acc){
  const int b  = blockIdx.x / (LL/CONV_LT);
  const int lt = blockIdx.x % (LL/CONV_LT);
  const int l0 = lt*CONV_LT;
  __shared__ float xt[(CONV_LT+62)*DD];   // 32.2 KB
  __shared__ float rs[256], rq[256];
  const int t = threadIdx.x;
  for (int i=t; i<(CONV_LT+62)*DD; i+=256){
    int lrel = i/DD, d = i%DD;
    int lg = l0 - 31 + lrel;
    xt[i] = (lg>=0 && lg<LL) ? x[((size_t)b*LL+lg)*DD + d] : 0.f;
  }
  __syncthreads();
  const int d = t & 63;
  const int base = (t >> 6) * 16;
  float acc[16];
  #pragma unroll
  for (int j=0;j<16;j++) acc[j]=0.f;
  #pragma unroll 1
  for (int kb=0; kb<4; ++kb){
    float wv[16];
    #pragma unroll
    for (int kk=0;kk<16;kk++){
      int k = kb*16+kk;
      wv[kk] = (k<KW) ? w[d*KW+k] : 0.f;
    }
    float xw[31];
    #pragma unroll
    for (int i=0;i<31;i++) xw[i] = xt[(base+kb*16+i)*DD + d];
    #pragma unroll
    for (int j=0;j<16;j++){
      #pragma unroll
      for (int kk=0;kk<16;kk++){
        acc[j] = fmaf(wv[kk], xw[j+kk], acc[j]);
      }
    }
  }
  float lsum=0.f, lsq=0.f;
  #pragma unroll
  for (int j=0;j<16;j++){
    xc[((size_t)b*LL + l0+base+j)*DD + d] = acc[j];
    lsum += acc[j]; lsq = fmaf(acc[j],acc[j],lsq);
  }
  rs[t]=lsum; rq[t]=lsq;
  __syncthreads();
  if (t<64){
    float s = rs[t]+rs[t+64]+rs[t+128]+rs[t+192];
    float q = rq[t]+rq[t+64]+rq[t+128]+rq[t+192];
    const int bkt = (blockIdx.x & (NBKT-1))*128;
    atomicAdd(&bn_acc[bkt+t],    s);
    atomicAdd(&bn_acc[bkt+64+t], q);
  }
}

// ---------------- K2: BN+SiLU ; x_proj ; merged dt-proj + chunk-local scan ----------
// thread (wv,d) owns positions wv*16..wv*16+15 -> u,delta live in registers
__global__ __launch_bounds__(256,4) void k_proj(const float* __restrict__ xc,
                                              const float* __restrict__ bn_acc,
                                              const float* __restrict__ gamma,
                                              const float* __restrict__ beta,
                                              const float* __restrict__ xpw,
                                              const float* __restrict__ dtw,
                                              const float* __restrict__ dtb,
                                              const float* __restrict__ Alog,
                                              float* __restrict__ duo,
                                              float* __restrict__ bc,
                                              float* __restrict__ chunkst){
  const int b  = blockIdx.x / (LL/PJ);
  const int lt = blockIdx.x % (LL/PJ);
  const int l0 = lt*PJ;
  __shared__ float ul[PJ*US];          // 17.4 KB
  __shared__ float bcl[PJ][24];        // 6 KB (slots 11,23 unused)
  __shared__ float wsh2[26*WS];        // 7.3 KB, c-major rows
  __shared__ float xd[PJ*NR];          // 1 KB
  __shared__ float dtwsh[64*NR];       // 1 KB
  const int t = threadIdx.x;
  for (int i=t; i<26*64; i+=256){ int c=i>>6, dd=i&63; wsh2[c*WS+dd] = xpw[i]; }
  dtwsh[t] = dtw[t];
  const int d = t & 63, wv = t >> 6;
  float msum = 0.f, qsum = 0.f;
  #pragma unroll
  for (int k=0;k<NBKT;k++){
    msum += bn_acc[k*128 + d];
    qsum += bn_acc[k*128 + 64 + d];
  }
  const float inv_n = 1.f/((float)NB*(float)LL);
  float mean = msum*inv_n;
  float var  = qsum*inv_n - mean*mean;
  float sc = gamma[d] * rsqrtf(var + 1e-5f);
  float sh = beta[d] - mean*sc;
  float uu[16];
  #pragma unroll
  for (int j=0;j<16;j++){
    int lr = wv*16 + j;
    float v = xc[((size_t)b*LL + l0+lr)*DD + d];
    v = fmaf(v, sc, sh);
    float u_ = v * sigmoidf_(v);
    uu[j] = u_;
    ul[lr*US+d] = u_;
  }
  __syncthreads();
  // x_proj matvec: 2 cols x 4 pos x 4-dd float4 blocking; unroll capped (no spill)
  {
    const int cp  = t & 15;            // c-pair 0..12 active
    const int lrb = t >> 4;            // position group 0..15
    if (cp < 13){
      float acc0[4] = {0.f,0.f,0.f,0.f};
      float acc1[4] = {0.f,0.f,0.f,0.f};
      #pragma unroll 2
      for (int dd4=0; dd4<16; ++dd4){
        float4 w0 = *reinterpret_cast<const float4*>(&wsh2[(2*cp  )*WS + dd4*4]);
        float4 w1 = *reinterpret_cast<const float4*>(&wsh2[(2*cp+1)*WS + dd4*4]);
        #pragma unroll
        for (int p=0;p<4;p++){
          float4 uv = *reinterpret_cast<const float4*>(&ul[(lrb*4+p)*US + dd4*4]);
          acc0[p] = fmaf(w0.x,uv.x, fmaf(w0.y,uv.y, fmaf(w0.z,uv.z, fmaf(w0.w,uv.w, acc0[p]))));
          acc1[p] = fmaf(w1.x,uv.x, fmaf(w1.y,uv.y, fmaf(w1.z,uv.z, fmaf(w1.w,uv.w, acc1[p]))));
        }
      }
      #pragma unroll
      for (int cc=0; cc<2; ++cc){
        int c = 2*cp+cc;
        #pragma unroll
        for (int p=0;p<4;p++){
          int lr = lrb*4+p;
          float v = cc ? acc1[p] : acc0[p];
          if (c < NR) xd[lr*NR+c] = v;
          else {
            int pos = c - NR;                       // B:0..10  C:11..21
            int slot = (pos < NS) ? pos : pos+1;    // pad slots 11 and 23
            bcl[lr][slot] = v;
            bc[((size_t)b*LL + l0+lr)*24 + slot] = v;
          }
        }
      }
    }
  }
  __syncthreads();
  // merged dt-proj + softplus + duo store + chunk-local scan (positions wv*16+l)
  {
    const float bias = dtb[d];
    const float dw0 = dtwsh[d*NR+0], dw1 = dtwsh[d*NR+1],
                dw2 = dtwsh[d*NR+2], dw3 = dtwsh[d*NR+3];
    float a0 = -__expf(Alog[d*NS]);
    bool fast = true;
    #pragma unroll
    for (int n=1;n<NS;n++){
      float an = -__expf(Alog[d*NS+n]);
      fast = fast && (fabsf(an - (float)(n+1)*a0) <= 1e-4f*(float)(n+1));
    }
    const int task = b*NC + lt*4 + wv;
    float h[12];
    #pragma unroll
    for (int n=0;n<12;n++) h[n]=0.f;
    float dsum=0.f;
    #pragma unroll 4
    for (int l=0;l<LC;++l){
      int lr = wv*LC + l;
      float4 xv = *reinterpret_cast<const float4*>(&xd[lr*NR]);
      float s = fmaf(dw0,xv.x, fmaf(dw1,xv.y, fmaf(dw2,xv.z, fmaf(dw3,xv.w, bias))));
      float de = fmaxf(s,0.f) + __logf(1.f + __expf(-fabsf(s)));
      float u_ = uu[l];
      float du = de*u_;
      dsum += de;
      float2 st; st.x = de; st.y = u_;
      *reinterpret_cast<float2*>(duo + (((size_t)b*LL + l0+lr)*DD + d)*2) = st;
      float bca[12];
      const float4* q = reinterpret_cast<const float4*>(&bcl[lr][0]);
      *reinterpret_cast<float4*>(&bca[0]) = q[0];
      *reinterpret_cast<float4*>(&bca[4]) = q[1];
      *reinterpret_cast<float4*>(&bca[8]) = q[2];
      if (fast){
        float r = __expf(a0*de);
        float dA = 1.f;
        #pragma unroll
        for (int n=0;n<NS;n++){
          dA *= r;
          h[n] = fmaf(dA, h[n], du*bca[n]);
        }
      } else {
        #pragma unroll
        for (int n=0;n<NS;n++){
          float dA = __expf(-__expf(Alog[d*NS+n])*de);
          h[n] = fmaf(dA, h[n], du*bca[n]);
        }
      }
    }
    h[11] = dsum;
    float4* o = reinterpret_cast<float4*>(chunkst + ((size_t)task*64 + d)*12);
    o[0] = *reinterpret_cast<float4*>(&h[0]);
    o[1] = *reinterpret_cast<float4*>(&h[4]);
    o[2] = *reinterpret_cast<float4*>(&h[8]);
  }
}

// ---------------- K4: cross-chunk propagation — one wave per (b,d) -----------------
__global__ __launch_bounds__(64) void k_scanMid(const float* __restrict__ chunkst,
                                                const float* __restrict__ Alog,
                                                float* __restrict__ hin){
  const int wid  = blockIdx.x;                        // 0..511 = b*64+d
  const int lane = threadIdx.x & 63;
  const int b = wid >> 6, d = wid & 63;
  const int c0 = lane*8;
  const size_t recbase = (((size_t)b*NC + c0)*64 + d)*12;   // + j*768
  float aAll[NS];
  #pragma unroll
  for (int n=0;n<NS;n++) aAll[n] = -expf(Alog[d*NS+n]);
  bool fast = true;
  #pragma unroll
  for (int n=1;n<NS;n++)
    fast = fast && (fabsf(aAll[n] - (float)(n+1)*aAll[0]) <= 1e-4f*(float)(n+1));
  float Aa[NS], Bb[NS];
  #pragma unroll
  for (int n=0;n<NS;n++){ Aa[n]=1.f; Bb[n]=0.f; }
  #pragma unroll
  for (int j=0;j<8;j++){
    float rec[12];
    const float4* q = reinterpret_cast<const float4*>(chunkst + recbase + (size_t)j*768);
    *reinterpret_cast<float4*>(&rec[0]) = q[0];
    *reinterpret_cast<float4*>(&rec[4]) = q[1];
    *reinterpret_cast<float4*>(&rec[8]) = q[2];
    float ds = rec[11];
    if (fast){
      float r = __expf(aAll[0]*ds);
      float dA = 1.f;
      #pragma unroll
      for (int n=0;n<NS;n++){
        dA *= r;
        Bb[n] = fmaf(dA, Bb[n], rec[n]);
        Aa[n] *= dA;
      }
    } else {
      #pragma unroll
      for (int n=0;n<NS;n++){
        float dA = __expf(aAll[n]*ds);
        Bb[n] = fmaf(dA, Bb[n], rec[n]);
        Aa[n] *= dA;
      }
    }
  }
  #pragma unroll
  for (int n=0;n<NS;n++){
    float A = Aa[n], Bv = Bb[n];
    #pragma unroll
    for (int off=1; off<64; off<<=1){
      float Ap=__shfl_up(A,off,64), Bp=__shfl_up(Bv,off,64);
      if (lane>=off){ Bv = fmaf(A,Bp,Bv); A*=Ap; }
    }
    float hs = __shfl_up(Bv,1,64);
    Bb[n] = (lane==0) ? 0.f : hs;     // h at chunk c0 (global h0=0)
  }
  #pragma unroll
  for (int j=0;j<8;j++){
    float rec[12];
    const float4* q = reinterpret_cast<const float4*>(chunkst + recbase + (size_t)j*768);
    *reinterpret_cast<float4*>(&rec[0]) = q[0];
    *reinterpret_cast<float4*>(&rec[4]) = q[1];
    *reinterpret_cast<float4*>(&rec[8]) = q[2];
    float ds = rec[11];
    float outv[12];
    if (fast){
      float r = __expf(aAll[0]*ds);
      float dA = 1.f;
      #pragma unroll
      for (int n=0;n<NS;n++){
        outv[n] = Bb[n];
        dA *= r;
        Bb[n] = fmaf(dA, Bb[n], rec[n]);
      }
    } else {
      #pragma unroll
      for (int n=0;n<NS;n++){
        outv[n] = Bb[n];
        float dA = __expf(aAll[n]*ds);
        Bb[n] = fmaf(dA, Bb[n], rec[n]);
      }
    }
    outv[11] = 0.f;
    float4* o = reinterpret_cast<float4*>(hin + recbase + (size_t)j*768);
    o[0] = *reinterpret_cast<float4*>(&outv[0]);
    o[1] = *reinterpret_cast<float4*>(&outv[4]);
    o[2] = *reinterpret_cast<float4*>(&outv[8]);
  }
}

// ---------------- K5: replay scan with h_in, y, RMSNorm over D, SiLU gating -------
__global__ __launch_bounds__(256,4) void k_scanB(const float* __restrict__ duo,
                                               const float* __restrict__ bc,
                                               const float* __restrict__ Alog,
                                               const float* __restrict__ hin,
                                               const float* __restrict__ Dsv,
                                               const float* __restrict__ rmss,
                                               const float* __restrict__ x,
                                               float* __restrict__ out){
  const int task = blockIdx.x*4 + (threadIdx.x>>6);
  const int d = threadIdx.x & 63;
  const int b = task / NC, c = task % NC;
  float a[NS], h[12];
  #pragma unroll
  for (int n=0;n<NS;n++) a[n] = -expf(Alog[d*NS+n]);
  bool fast = true;
  #pragma unroll
  for (int n=1;n<NS;n++)
    fast = fast && (fabsf(a[n] - (float)(n+1)*a[0]) <= 1e-4f*(float)(n+1));
  {
    const float4* q = reinterpret_cast<const float4*>(hin + ((size_t)task*64 + d)*12);
    *reinterpret_cast<float4*>(&h[0]) = q[0];
    *reinterpret_cast<float4*>(&h[4]) = q[1];
    *reinterpret_cast<float4*>(&h[8]) = q[2];
  }
  const float Dd = Dsv[d];
  const float rsc = rmss[d];
  const int l0 = c*LC;
  #pragma unroll 2
  for (int l=l0; l<l0+LC; ++l){
    size_t p = (size_t)b*LL + l;
    float2 du2 = *reinterpret_cast<const float2*>(duo + (p*DD+d)*2);
    float de = du2.x, uu = du2.y;
    float du = de*uu;
    float bca[24];
    const float4* q = reinterpret_cast<const float4*>(bc + p*24);
    *reinterpret_cast<float4*>(&bca[0])  = q[0];
    *reinterpret_cast<float4*>(&bca[4])  = q[1];
    *reinterpret_cast<float4*>(&bca[8])  = q[2];
    *reinterpret_cast<float4*>(&bca[12]) = q[3];
    *reinterpret_cast<float4*>(&bca[16]) = q[4];
    *reinterpret_cast<float4*>(&bca[20]) = q[5];
    float y = Dd*uu;
    if (fast){
      float r = __expf(a[0]*de);
      float dA = 1.f;
      #pragma unroll
      for (int n=0;n<NS;n++){
        dA *= r;
        h[n] = fmaf(dA, h[n], du*bca[n]);
        y = fmaf(h[n], bca[12+n], y);
      }
    } else {
      #pragma unroll
      for (int n=0;n<NS;n++){
        float dA = __expf(a[n]*de);
        h[n] = fmaf(dA, h[n], du*bca[n]);
        y = fmaf(h[n], bca[12+n], y);
      }
    }
    float ss = y*y;
    #pragma unroll
    for (int m=1;m<64;m<<=1) ss += __shfl_xor(ss, m, 64);
    float yn = rsc * rsqrtf(ss*(1.f/64.f) + 1e-5f) * y;
    float z = x[p*DD+d];
    out[p*DD+d] = yn * (z * sigmoidf_(z));
  }
}

extern "C" void kernel_launch(void* const* d_in, const int* in_sizes, int n_in,
                              void* d_out, int out_size, void* d_ws, size_t ws_size,
                              hipStream_t stream) {
  const float* x     = (const float*)d_in[0];
  const float* w     = (const float*)d_in[1];
  const float* gamma = (const float*)d_in[2];
  const float* beta  = (const float*)d_in[3];
  const float* xpw   = (const float*)d_in[4];
  const float* dtw   = (const float*)d_in[5];
  const float* dtb   = (const float*)d_in[6];
  const float* Alog  = (const float*)d_in[7];
  const float* Dsv   = (const float*)d_in[8];
  const float* rmss  = (const float*)d_in[9];
  float* out = (float*)d_out;

  float* f = (float*)d_ws;
  const size_t n_xld = (size_t)NB*LL*DD;       // 4,194,304
  float* xc      = f;                          // conv out
  float* duo     = xc + n_xld;                 // (b,l,d,2): delta, u
  float* bc      = duo + 2*n_xld;              // (b,l,24): B[0..10],pad,C[0..10],pad
  float* chunkst = bc + (size_t)NB*LL*24;      // (b,c,d,12): h_end[0..10], dsum
  float* hin     = chunkst + (size_t)NB*NC*64*12;  // (b,c,d,12): h_in[0..10], pad
  float* bn_acc  = hin + (size_t)NB*NC*64*12;      // 16 buckets x 128

  k_zero   <<<NBKT*128/256, 256, 0, stream>>>(bn_acc);
  k_conv   <<<NB*(LL/CONV_LT), 256, 0, stream>>>(x, w, xc, bn_acc);
  k_proj   <<<NB*(LL/PJ), 256, 0, stream>>>(xc, bn_acc, gamma, beta, xpw, dtw, dtb, Alog, duo, bc, chunkst);
  k_scanMid<<<NB*DD, 64, 0, stream>>>(chunkst, Alog, hin);
  k_scanB  <<<(NB*NC)/4, 256, 0, stream>>>(duo, bc, Alog, hin, Dsv, rmss, x, out);
}

// Round 17
// 90.480 us; speedup vs baseline: 1.3094x; 1.0511x over previous
//
#include <hip/hip_runtime.h>
#include <hip/hip_bf16.h>
#include <math.h>

#define NB 8
#define LL 8192
#define DD 64
#define NS 11
#define NR 4
#define NC 512        // chunks
#define LC (LL/NC)    // 16 positions per chunk
#define CONV_LT 128
#define KW 63
#define PJ 64         // proj tile = 4 chunks
#define NBKT 64       // BN atomic buckets (8-deep chains at 512 conv blocks)
#define US 68         // LDS row stride for ul (16-bank shift per row, 16B aligned)
#define WS 72         // LDS row stride for wsh2

__device__ __forceinline__ float sigmoidf_(float v){ return 1.f/(1.f+__expf(-v)); }

// ---------------- K0: zero the BN accumulator ----------------
__global__ void k_zero(float* __restrict__ p){
  p[blockIdx.x*256 + threadIdx.x] = 0.f;
}

// ---------------- K1: depthwise conv (k=63, pad 31) + bucketed BN partial sums ------
// CONV_LT=128, 512 threads (8 waves x 16 positions); dense 16x16 FMA inner block
__global__ __launch_bounds__(512,4) void k_conv(const float* __restrict__ x,
                                              const float* __restrict__ w,
                                              float* __restrict__ xc,
                                              float* __restrict__ bn_acc){
  const int b  = blockIdx.x / (LL/CONV_LT);
  const int lt = blockIdx.x % (LL/CONV_LT);
  const int l0 = lt*CONV_LT;
  __shared__ float xt[(CONV_LT+62)*DD];   // 47.5 KB
  __shared__ float rs[512], rq[512];
  const int t = threadIdx.x;
  for (int i=t; i<(CONV_LT+62)*DD; i+=512){
    int lrel = i/DD, d = i%DD;
    int lg = l0 - 31 + lrel;
    xt[i] = (lg>=0 && lg<LL) ? x[((size_t)b*LL+lg)*DD + d] : 0.f;
  }
  __syncthreads();
  const int d = t & 63;
  const int base = (t >> 6) * 16;       // 8 waves x 16 positions
  float acc[16];
  #pragma unroll
  for (int j=0;j<16;j++) acc[j]=0.f;
  #pragma unroll 1
  for (int kb=0; kb<4; ++kb){
    float wv[16];
    #pragma unroll
    for (int kk=0;kk<16;kk++){
      int k = kb*16+kk;
      wv[kk] = (k<KW) ? w[d*KW+k] : 0.f;
    }
    float xw[31];
    #pragma unroll
    for (int i=0;i<31;i++) xw[i] = xt[(base+kb*16+i)*DD + d];
    #pragma unroll
    for (int j=0;j<16;j++){
      #pragma unroll
      for (int kk=0;kk<16;kk++){
        acc[j] = fmaf(wv[kk], xw[j+kk], acc[j]);
      }
    }
  }
  float lsum=0.f, lsq=0.f;
  #pragma unroll
  for (int j=0;j<16;j++){
    xc[((size_t)b*LL + l0+base+j)*DD + d] = acc[j];
    lsum += acc[j]; lsq = fmaf(acc[j],acc[j],lsq);
  }
  rs[t]=lsum; rq[t]=lsq;
  __syncthreads();
  if (t<64){
    float s=0.f, q=0.f;
    #pragma unroll
    for (int g=0; g<8; ++g){ s += rs[t+64*g]; q += rq[t+64*g]; }
    const int bkt = (blockIdx.x & (NBKT-1))*128;
    atomicAdd(&bn_acc[bkt+t],    s);
    atomicAdd(&bn_acc[bkt+64+t], q);
  }
}

// ---------------- K2: BN+SiLU ; x_proj ; merged dt-proj + chunk-local scan ----------
__global__ __launch_bounds__(256,4) void k_proj(const float* __restrict__ xc,
                                              const float* __restrict__ bn_acc,
                                              const float* __restrict__ gamma,
                                              const float* __restrict__ beta,
                                              const float* __restrict__ xpw,
                                              const float* __restrict__ dtw,
                                              const float* __restrict__ dtb,
                                              const float* __restrict__ Alog,
                                              float* __restrict__ duo,
                                              float* __restrict__ bc,
                                              float* __restrict__ chunkst){
  const int b  = blockIdx.x / (LL/PJ);
  const int lt = blockIdx.x % (LL/PJ);
  const int l0 = lt*PJ;
  __shared__ float ul[PJ*US];          // 17.4 KB
  __shared__ float bcl[PJ][24];        // 6 KB
  __shared__ float wsh2[26*WS];        // 7.3 KB, c-major rows
  __shared__ float xd[PJ*NR];          // 1 KB
  __shared__ float dtwsh[64*NR];       // 1 KB
  __shared__ float bnred[2][4][64];    // 2 KB
  const int t = threadIdx.x;
  for (int i=t; i<26*64; i+=256){ int c=i>>6, dd=i&63; wsh2[c*WS+dd] = xpw[i]; }
  dtwsh[t] = dtw[t];
  const int d = t & 63, wv = t >> 6;
  {
    float ms=0.f, qs=0.f;
    #pragma unroll
    for (int k=wv*16; k<wv*16+16; ++k){
      ms += bn_acc[k*128 + d];
      qs += bn_acc[k*128 + 64 + d];
    }
    bnred[0][wv][d]=ms; bnred[1][wv][d]=qs;
  }
  __syncthreads();
  float msum = bnred[0][0][d]+bnred[0][1][d]+bnred[0][2][d]+bnred[0][3][d];
  float qsum = bnred[1][0][d]+bnred[1][1][d]+bnred[1][2][d]+bnred[1][3][d];
  const float inv_n = 1.f/((float)NB*(float)LL);
  float mean = msum*inv_n;
  float var  = qsum*inv_n - mean*mean;
  float sc = gamma[d] * rsqrtf(var + 1e-5f);
  float sh = beta[d] - mean*sc;
  float uu[16];
  #pragma unroll
  for (int j=0;j<16;j++){
    int lr = wv*16 + j;
    float v = xc[((size_t)b*LL + l0+lr)*DD + d];
    v = fmaf(v, sc, sh);
    float u_ = v * sigmoidf_(v);
    uu[j] = u_;
    ul[lr*US+d] = u_;
  }
  __syncthreads();
  // x_proj matvec: 2 cols x 4 pos x 4-dd float4 blocking; unroll capped (no spill)
  {
    const int cp  = t & 15;
    const int lrb = t >> 4;
    if (cp < 13){
      float acc0[4] = {0.f,0.f,0.f,0.f};
      float acc1[4] = {0.f,0.f,0.f,0.f};
      #pragma unroll 2
      for (int dd4=0; dd4<16; ++dd4){
        float4 w0 = *reinterpret_cast<const float4*>(&wsh2[(2*cp  )*WS + dd4*4]);
        float4 w1 = *reinterpret_cast<const float4*>(&wsh2[(2*cp+1)*WS + dd4*4]);
        #pragma unroll
        for (int p=0;p<4;p++){
          float4 uv = *reinterpret_cast<const float4*>(&ul[(lrb*4+p)*US + dd4*4]);
          acc0[p] = fmaf(w0.x,uv.x, fmaf(w0.y,uv.y, fmaf(w0.z,uv.z, fmaf(w0.w,uv.w, acc0[p]))));
          acc1[p] = fmaf(w1.x,uv.x, fmaf(w1.y,uv.y, fmaf(w1.z,uv.z, fmaf(w1.w,uv.w, acc1[p]))));
        }
      }
      #pragma unroll
      for (int cc=0; cc<2; ++cc){
        int c = 2*cp+cc;
        #pragma unroll
        for (int p=0;p<4;p++){
          int lr = lrb*4+p;
          float v = cc ? acc1[p] : acc0[p];
          if (c < NR) xd[lr*NR+c] = v;
          else {
            int pos = c - NR;                       // B:0..10  C:11..21
            int slot = (pos < NS) ? pos : pos+1;    // pad slots 11 and 23
            bcl[lr][slot] = v;
            bc[((size_t)b*LL + l0+lr)*24 + slot] = v;
          }
        }
      }
    }
  }
  __syncthreads();
  // merged dt-proj + softplus + paired duo store + chunk-local scan
  {
    const float bias = dtb[d];
    const float dw0 = dtwsh[d*NR+0], dw1 = dtwsh[d*NR+1],
                dw2 = dtwsh[d*NR+2], dw3 = dtwsh[d*NR+3];
    float a0 = -__expf(Alog[d*NS]);
    bool fast = true;
    #pragma unroll
    for (int n=1;n<NS;n++){
      float an = -__expf(Alog[d*NS+n]);
      fast = fast && (fabsf(an - (float)(n+1)*a0) <= 1e-4f*(float)(n+1));
    }
    const int task = b*NC + lt*4 + wv;
    float h[12];
    #pragma unroll
    for (int n=0;n<12;n++) h[n]=0.f;
    float dsum=0.f;
    float de_prev=0.f, u_prev=0.f;
    #pragma unroll 4
    for (int l=0;l<LC;++l){
      int lr = wv*LC + l;
      float4 xv = *reinterpret_cast<const float4*>(&xd[lr*NR]);
      float s = fmaf(dw0,xv.x, fmaf(dw1,xv.y, fmaf(dw2,xv.z, fmaf(dw3,xv.w, bias))));
      float de = fmaxf(s,0.f) + __logf(1.f + __expf(-fabsf(s)));
      float u_ = uu[l];
      float du = de*u_;
      dsum += de;
      if ((l & 1)==0){ de_prev = de; u_prev = u_; }
      else {
        float4 st; st.x = de_prev; st.y = u_prev; st.z = de; st.w = u_;
        size_t ph = (size_t)b*(LL/2) + (size_t)(l0 + lr - 1)/2;
        *reinterpret_cast<float4*>(duo + (ph*DD + d)*4) = st;
      }
      float bca[12];
      const float4* q = reinterpret_cast<const float4*>(&bcl[lr][0]);
      *reinterpret_cast<float4*>(&bca[0]) = q[0];
      *reinterpret_cast<float4*>(&bca[4]) = q[1];
      *reinterpret_cast<float4*>(&bca[8]) = q[2];
      if (fast){
        float r = __expf(a0*de);
        float dA = 1.f;
        #pragma unroll
        for (int n=0;n<NS;n++){
          dA *= r;
          h[n] = fmaf(dA, h[n], du*bca[n]);
        }
      } else {
        #pragma unroll
        for (int n=0;n<NS;n++){
          float dA = __expf(-__expf(Alog[d*NS+n])*de);
          h[n] = fmaf(dA, h[n], du*bca[n]);
        }
      }
    }
    h[11] = dsum;
    float4* o = reinterpret_cast<float4*>(chunkst + ((size_t)task*64 + d)*12);
    o[0] = *reinterpret_cast<float4*>(&h[0]);
    o[1] = *reinterpret_cast<float4*>(&h[4]);
    o[2] = *reinterpret_cast<float4*>(&h[8]);
  }
}

// ---------------- K4: cross-chunk propagation — one wave per (b,d) -----------------
__global__ __launch_bounds__(64) void k_scanMid(const float* __restrict__ chunkst,
                                                const float* __restrict__ Alog,
                                                float* __restrict__ hin){
  const int wid  = blockIdx.x;                        // 0..511 = b*64+d
  const int lane = threadIdx.x & 63;
  const int b = wid >> 6, d = wid & 63;
  const int c0 = lane*8;
  const size_t recbase = (((size_t)b*NC + c0)*64 + d)*12;   // + j*768
  float aAll[NS];
  #pragma unroll
  for (int n=0;n<NS;n++) aAll[n] = -expf(Alog[d*NS+n]);
  bool fast = true;
  #pragma unroll
  for (int n=1;n<NS;n++)
    fast = fast && (fabsf(aAll[n] - (float)(n+1)*aAll[0]) <= 1e-4f*(float)(n+1));
  float Aa[NS], Bb[NS];
  #pragma unroll
  for (int n=0;n<NS;n++){ Aa[n]=1.f; Bb[n]=0.f; }
  #pragma unroll
  for (int j=0;j<8;j++){
    float rec[12];
    const float4* q = reinterpret_cast<const float4*>(chunkst + recbase + (size_t)j*768);
    *reinterpret_cast<float4*>(&rec[0]) = q[0];
    *reinterpret_cast<float4*>(&rec[4]) = q[1];
    *reinterpret_cast<float4*>(&rec[8]) = q[2];
    float ds = rec[11];
    if (fast){
      float r = __expf(aAll[0]*ds);
      float dA = 1.f;
      #pragma unroll
      for (int n=0;n<NS;n++){
        dA *= r;
        Bb[n] = fmaf(dA, Bb[n], rec[n]);
        Aa[n] *= dA;
      }
    } else {
      #pragma unroll
      for (int n=0;n<NS;n++){
        float dA = __expf(aAll[n]*ds);
        Bb[n] = fmaf(dA, Bb[n], rec[n]);
        Aa[n] *= dA;
      }
    }
  }
  #pragma unroll
  for (int n=0;n<NS;n++){
    float A = Aa[n], Bv = Bb[n];
    #pragma unroll
    for (int off=1; off<64; off<<=1){
      float Ap=__shfl_up(A,off,64), Bp=__shfl_up(Bv,off,64);
      if (lane>=off){ Bv = fmaf(A,Bp,Bv); A*=Ap; }
    }
    float hs = __shfl_up(Bv,1,64);
    Bb[n] = (lane==0) ? 0.f : hs;     // h at chunk c0 (global h0=0)
  }
  #pragma unroll
  for (int j=0;j<8;j++){
    float rec[12];
    const float4* q = reinterpret_cast<const float4*>(chunkst + recbase + (size_t)j*768);
    *reinterpret_cast<float4*>(&rec[0]) = q[0];
    *reinterpret_cast<float4*>(&rec[4]) = q[1];
    *reinterpret_cast<float4*>(&rec[8]) = q[2];
    float ds = rec[11];
    float outv[12];
    if (fast){
      float r = __expf(aAll[0]*ds);
      float dA = 1.f;
      #pragma unroll
      for (int n=0;n<NS;n++){
        outv[n] = Bb[n];
        dA *= r;
        Bb[n] = fmaf(dA, Bb[n], rec[n]);
      }
    } else {
      #pragma unroll
      for (int n=0;n<NS;n++){
        outv[n] = Bb[n];
        float dA = __expf(aAll[n]*ds);
        Bb[n] = fmaf(dA, Bb[n], rec[n]);
      }
    }
    outv[11] = 0.f;
    float4* o = reinterpret_cast<float4*>(hin + recbase + (size_t)j*768);
    o[0] = *reinterpret_cast<float4*>(&outv[0]);
    o[1] = *reinterpret_cast<float4*>(&outv[4]);
    o[2] = *reinterpret_cast<float4*>(&outv[8]);
  }
}

// ---------------- K5: replay scan with h_in, y, RMSNorm over D, SiLU gating -------
__global__ __launch_bounds__(256,4) void k_scanB(const float* __restrict__ duo,
                                               const float* __restrict__ bc,
                                               const float* __restrict__ Alog,
                                               const float* __restrict__ hin,
                                               const float* __restrict__ Dsv,
                                               const float* __restrict__ rmss,
                                               const float* __restrict__ x,
                                               float* __restrict__ out){
  const int task = blockIdx.x*4 + (threadIdx.x>>6);
  const int d = threadIdx.x & 63;
  const int b = task / NC, c = task % NC;
  float a0 = -expf(Alog[d*NS]);
  bool fast = true;
  #pragma unroll
  for (int n=1;n<NS;n++){
    float an = -expf(Alog[d*NS+n]);
    fast = fast && (fabsf(an - (float)(n+1)*a0) <= 1e-4f*(float)(n+1));
  }
  float h[12];
  {
    const float4* q = reinterpret_cast<const float4*>(hin + ((size_t)task*64 + d)*12);
    *reinterpret_cast<float4*>(&h[0]) = q[0];
    *reinterpret_cast<float4*>(&h[4]) = q[1];
    *reinterpret_cast<float4*>(&h[8]) = q[2];
  }
  const float Dd = Dsv[d];
  const float rsc = rmss[d];
  const int l0 = c*LC;
  #pragma unroll 2
  for (int l2=0; l2<LC; l2+=2){
    size_t ph = (size_t)b*(LL/2) + (size_t)(l0+l2)/2;
    float4 dq = *reinterpret_cast<const float4*>(duo + (ph*DD + d)*4);
    #pragma unroll
    for (int s=0; s<2; ++s){
      size_t p = (size_t)b*LL + l0 + l2 + s;
      float de = s ? dq.z : dq.x;
      float uu = s ? dq.w : dq.y;
      float du = de*uu;
      float bca[24];
      const float4* q = reinterpret_cast<const float4*>(bc + p*24);
      *reinterpret_cast<float4*>(&bca[0])  = q[0];
      *reinterpret_cast<float4*>(&bca[4])  = q[1];
      *reinterpret_cast<float4*>(&bca[8])  = q[2];
      *reinterpret_cast<float4*>(&bca[12]) = q[3];
      *reinterpret_cast<float4*>(&bca[16]) = q[4];
      *reinterpret_cast<float4*>(&bca[20]) = q[5];
      float y = Dd*uu;
      if (fast){
        float r = __expf(a0*de);
        float dA = 1.f;
        #pragma unroll
        for (int n=0;n<NS;n++){
          dA *= r;
          h[n] = fmaf(dA, h[n], du*bca[n]);
          y = fmaf(h[n], bca[12+n], y);
        }
      } else {
        #pragma unroll
        for (int n=0;n<NS;n++){
          float dA = __expf(-expf(Alog[d*NS+n])*de);
          h[n] = fmaf(dA, h[n], du*bca[n]);
          y = fmaf(h[n], bca[12+n], y);
        }
      }
      float ss = y*y;
      #pragma unroll
      for (int m=1;m<64;m<<=1) ss += __shfl_xor(ss, m, 64);
      float yn = rsc * rsqrtf(ss*(1.f/64.f) + 1e-5f) * y;
      float z = x[p*DD+d];
      out[p*DD+d] = yn * (z * sigmoidf_(z));
    }
  }
}

extern "C" void kernel_launch(void* const* d_in, const int* in_sizes, int n_in,
                              void* d_out, int out_size, void* d_ws, size_t ws_size,
                              hipStream_t stream) {
  const float* x     = (const float*)d_in[0];
  const float* w     = (const float*)d_in[1];
  const float* gamma = (const float*)d_in[2];
  const float* beta  = (const float*)d_in[3];
  const float* xpw   = (const float*)d_in[4];
  const float* dtw   = (const float*)d_in[5];
  const float* dtb   = (const float*)d_in[6];
  const float* Alog  = (const float*)d_in[7];
  const float* Dsv   = (const float*)d_in[8];
  const float* rmss  = (const float*)d_in[9];
  float* out = (float*)d_out;

  float* f = (float*)d_ws;
  const size_t n_xld = (size_t)NB*LL*DD;       // 4,194,304
  float* xc      = f;                          // conv out
  float* duo     = xc + n_xld;                 // (b, l/2, d, 4): d0,u0,d1,u1
  float* bc      = duo + 2*n_xld;              // (b,l,24): B[0..10],pad,C[0..10],pad
  float* chunkst = bc + (size_t)NB*LL*24;      // (b,c,d,12): h_end[0..10], dsum
  float* hin     = chunkst + (size_t)NB*NC*64*12;  // (b,c,d,12): h_in[0..10], pad
  float* bn_acc  = hin + (size_t)NB*NC*64*12;      // 64 buckets x 128

  k_zero   <<<NBKT*128/256, 256, 0, stream>>>(bn_acc);
  k_conv   <<<NB*(LL/CONV_LT), 512, 0, stream>>>(x, w, xc, bn_acc);
  k_proj   <<<NB*(LL/PJ), 256, 0, stream>>>(xc, bn_acc, gamma, beta, xpw, dtw, dtb, Alog, duo, bc, chunkst);
  k_scanMid<<<NB*DD, 64, 0, stream>>>(chunkst, Alog, hin);
  k_scanB  <<<(NB*NC)/4, 256, 0, stream>>>(duo, bc, Alog, hin, Dsv, rmss, x, out);
}

// Round 18
// 89.144 us; speedup vs baseline: 1.3291x; 1.0150x over previous
//
#include <hip/hip_runtime.h>
#include <hip/hip_bf16.h>
#include <hip/hip_fp16.h>
#include <math.h>

#define NB 8
#define LL 8192
#define DD 64
#define NS 11
#define NR 4
#define NC 512        // chunks
#define LC (LL/NC)    // 16 positions per chunk
#define CONV_LT 128
#define KW 63
#define PJ 64         // proj tile = 4 chunks
#define NBKT 64       // BN atomic buckets
#define US 68         // LDS row stride for ul
#define WS 72         // LDS row stride for wsh2

__device__ __forceinline__ float sigmoidf_(float v){ return 1.f/(1.f+__expf(-v)); }
__device__ __forceinline__ float rnd16(float v){ return __half2float(__float2half_rn(v)); }

// ---------------- K0: zero the BN accumulator ----------------
__global__ void k_zero(float* __restrict__ p){
  p[blockIdx.x*256 + threadIdx.x] = 0.f;
}

// ---------------- K1: depthwise conv (k=63, pad 31) + bucketed BN partial sums ------
__global__ __launch_bounds__(512,4) void k_conv(const float* __restrict__ x,
                                              const float* __restrict__ w,
                                              __half* __restrict__ xc,
                                              float* __restrict__ bn_acc){
  const int b  = blockIdx.x / (LL/CONV_LT);
  const int lt = blockIdx.x % (LL/CONV_LT);
  const int l0 = lt*CONV_LT;
  __shared__ float xt[(CONV_LT+62)*DD];   // 47.5 KB
  __shared__ float rs[512], rq[512];
  const int t = threadIdx.x;
  for (int i=t; i<(CONV_LT+62)*DD; i+=512){
    int lrel = i/DD, d = i%DD;
    int lg = l0 - 31 + lrel;
    xt[i] = (lg>=0 && lg<LL) ? x[((size_t)b*LL+lg)*DD + d] : 0.f;
  }
  __syncthreads();
  const int d = t & 63;
  const int base = (t >> 6) * 16;       // 8 waves x 16 positions
  float acc[16];
  #pragma unroll
  for (int j=0;j<16;j++) acc[j]=0.f;
  #pragma unroll 1
  for (int kb=0; kb<4; ++kb){
    float wv[16];
    #pragma unroll
    for (int kk=0;kk<16;kk++){
      int k = kb*16+kk;
      wv[kk] = (k<KW) ? w[d*KW+k] : 0.f;
    }
    float xw[31];
    #pragma unroll
    for (int i=0;i<31;i++) xw[i] = xt[(base+kb*16+i)*DD + d];
    #pragma unroll
    for (int j=0;j<16;j++){
      #pragma unroll
      for (int kk=0;kk<16;kk++){
        acc[j] = fmaf(wv[kk], xw[j+kk], acc[j]);
      }
    }
  }
  float lsum=0.f, lsq=0.f;
  #pragma unroll
  for (int j=0;j<16;j++){
    xc[((size_t)b*LL + l0+base+j)*DD + d] = __float2half_rn(acc[j]);
    lsum += acc[j]; lsq = fmaf(acc[j],acc[j],lsq);
  }
  rs[t]=lsum; rq[t]=lsq;
  __syncthreads();
  if (t<64){
    float s=0.f, q=0.f;
    #pragma unroll
    for (int g=0; g<8; ++g){ s += rs[t+64*g]; q += rq[t+64*g]; }
    const int bkt = (blockIdx.x & (NBKT-1))*128;
    atomicAdd(&bn_acc[bkt+t],    s);
    atomicAdd(&bn_acc[bkt+64+t], q);
  }
}

// ---------------- K2: BN+SiLU ; x_proj ; merged dt-proj + chunk-local scan ----------
__global__ __launch_bounds__(256,4) void k_proj(const __half* __restrict__ xc,
                                              const float* __restrict__ bn_acc,
                                              const float* __restrict__ gamma,
                                              const float* __restrict__ beta,
                                              const float* __restrict__ xpw,
                                              const float* __restrict__ dtw,
                                              const float* __restrict__ dtb,
                                              const float* __restrict__ Alog,
                                              __half2* __restrict__ duo,
                                              __half* __restrict__ bch,
                                              float* __restrict__ chunkst){
  const int b  = blockIdx.x / (LL/PJ);
  const int lt = blockIdx.x % (LL/PJ);
  const int l0 = lt*PJ;
  __shared__ float ul[PJ*US];          // 17.4 KB
  __shared__ float bcl[PJ][24];        // 6 KB
  __shared__ float wsh2[26*WS];        // 7.3 KB
  __shared__ float xd[PJ*NR];          // 1 KB
  __shared__ float dtwsh[64*NR];       // 1 KB
  __shared__ float bnred[2][4][64];    // 2 KB
  const int t = threadIdx.x;
  for (int i=t; i<26*64; i+=256){ int c=i>>6, dd=i&63; wsh2[c*WS+dd] = xpw[i]; }
  dtwsh[t] = dtw[t];
  const int d = t & 63, wv = t >> 6;
  {
    float ms=0.f, qs=0.f;
    #pragma unroll
    for (int k=wv*16; k<wv*16+16; ++k){
      ms += bn_acc[k*128 + d];
      qs += bn_acc[k*128 + 64 + d];
    }
    bnred[0][wv][d]=ms; bnred[1][wv][d]=qs;
  }
  __syncthreads();
  float msum = bnred[0][0][d]+bnred[0][1][d]+bnred[0][2][d]+bnred[0][3][d];
  float qsum = bnred[1][0][d]+bnred[1][1][d]+bnred[1][2][d]+bnred[1][3][d];
  const float inv_n = 1.f/((float)NB*(float)LL);
  float mean = msum*inv_n;
  float var  = qsum*inv_n - mean*mean;
  float sc = gamma[d] * rsqrtf(var + 1e-5f);
  float sh = beta[d] - mean*sc;
  float uu[16];
  #pragma unroll
  for (int j=0;j<16;j++){
    int lr = wv*16 + j;
    float v = __half2float(xc[((size_t)b*LL + l0+lr)*DD + d]);
    v = fmaf(v, sc, sh);
    float u_ = rnd16(v * sigmoidf_(v));     // fp16-consistent with scanB
    uu[j] = u_;
    ul[lr*US+d] = u_;
  }
  __syncthreads();
  // x_proj matvec: 2 cols x 4 pos x 4-dd float4 blocking
  {
    const int cp  = t & 15;
    const int lrb = t >> 4;
    if (cp < 13){
      float acc0[4] = {0.f,0.f,0.f,0.f};
      float acc1[4] = {0.f,0.f,0.f,0.f};
      #pragma unroll 2
      for (int dd4=0; dd4<16; ++dd4){
        float4 w0 = *reinterpret_cast<const float4*>(&wsh2[(2*cp  )*WS + dd4*4]);
        float4 w1 = *reinterpret_cast<const float4*>(&wsh2[(2*cp+1)*WS + dd4*4]);
        #pragma unroll
        for (int p=0;p<4;p++){
          float4 uv = *reinterpret_cast<const float4*>(&ul[(lrb*4+p)*US + dd4*4]);
          acc0[p] = fmaf(w0.x,uv.x, fmaf(w0.y,uv.y, fmaf(w0.z,uv.z, fmaf(w0.w,uv.w, acc0[p]))));
          acc1[p] = fmaf(w1.x,uv.x, fmaf(w1.y,uv.y, fmaf(w1.z,uv.z, fmaf(w1.w,uv.w, acc1[p]))));
        }
      }
      #pragma unroll
      for (int cc=0; cc<2; ++cc){
        int c = 2*cp+cc;
        #pragma unroll
        for (int p=0;p<4;p++){
          int lr = lrb*4+p;
          float v = cc ? acc1[p] : acc0[p];
          if (c < NR) xd[lr*NR+c] = v;
          else {
            int pos = c - NR;                       // B:0..10  C:11..21
            int slot = (pos < NS) ? pos : pos+1;    // pad slots 11 and 23
            float vr = rnd16(v);                    // fp16-consistent
            bcl[lr][slot] = vr;
            bch[((size_t)b*LL + l0+lr)*24 + slot] = __float2half_rn(v);
          }
        }
      }
    }
  }
  __syncthreads();
  // merged dt-proj + softplus + duo(half2) store + chunk-local scan
  {
    const float bias = dtb[d];
    const float dw0 = dtwsh[d*NR+0], dw1 = dtwsh[d*NR+1],
                dw2 = dtwsh[d*NR+2], dw3 = dtwsh[d*NR+3];
    float a0 = -__expf(Alog[d*NS]);
    bool fast = true;
    #pragma unroll
    for (int n=1;n<NS;n++){
      float an = -__expf(Alog[d*NS+n]);
      fast = fast && (fabsf(an - (float)(n+1)*a0) <= 1e-4f*(float)(n+1));
    }
    const int task = b*NC + lt*4 + wv;
    float h[12];
    #pragma unroll
    for (int n=0;n<12;n++) h[n]=0.f;
    float dsum=0.f;
    #pragma unroll 4
    for (int l=0;l<LC;++l){
      int lr = wv*LC + l;
      float4 xv = *reinterpret_cast<const float4*>(&xd[lr*NR]);
      float s = fmaf(dw0,xv.x, fmaf(dw1,xv.y, fmaf(dw2,xv.z, fmaf(dw3,xv.w, bias))));
      float de = rnd16(fmaxf(s,0.f) + __logf(1.f + __expf(-fabsf(s))));
      float u_ = uu[l];
      float du = de*u_;
      dsum += de;
      duo[((size_t)b*LL + l0+lr)*DD + d] = __floats2half2_rn(de, u_);
      float bca[12];
      const float4* q = reinterpret_cast<const float4*>(&bcl[lr][0]);
      *reinterpret_cast<float4*>(&bca[0]) = q[0];
      *reinterpret_cast<float4*>(&bca[4]) = q[1];
      *reinterpret_cast<float4*>(&bca[8]) = q[2];
      if (fast){
        float r = __expf(a0*de);
        float dA = 1.f;
        #pragma unroll
        for (int n=0;n<NS;n++){
          dA *= r;
          h[n] = fmaf(dA, h[n], du*bca[n]);
        }
      } else {
        #pragma unroll
        for (int n=0;n<NS;n++){
          float dA = __expf(-__expf(Alog[d*NS+n])*de);
          h[n] = fmaf(dA, h[n], du*bca[n]);
        }
      }
    }
    h[11] = dsum;
    float4* o = reinterpret_cast<float4*>(chunkst + ((size_t)task*64 + d)*12);
    o[0] = *reinterpret_cast<float4*>(&h[0]);
    o[1] = *reinterpret_cast<float4*>(&h[4]);
    o[2] = *reinterpret_cast<float4*>(&h[8]);
  }
}

// ---------------- K4: cross-chunk propagation — one wave per (b,d) -----------------
__global__ __launch_bounds__(64) void k_scanMid(const float* __restrict__ chunkst,
                                                const float* __restrict__ Alog,
                                                float* __restrict__ hin){
  const int wid  = blockIdx.x;
  const int lane = threadIdx.x & 63;
  const int b = wid >> 6, d = wid & 63;
  const int c0 = lane*8;
  const size_t recbase = (((size_t)b*NC + c0)*64 + d)*12;
  float aAll[NS];
  #pragma unroll
  for (int n=0;n<NS;n++) aAll[n] = -expf(Alog[d*NS+n]);
  bool fast = true;
  #pragma unroll
  for (int n=1;n<NS;n++)
    fast = fast && (fabsf(aAll[n] - (float)(n+1)*aAll[0]) <= 1e-4f*(float)(n+1));
  float Aa[NS], Bb[NS];
  #pragma unroll
  for (int n=0;n<NS;n++){ Aa[n]=1.f; Bb[n]=0.f; }
  #pragma unroll
  for (int j=0;j<8;j++){
    float rec[12];
    const float4* q = reinterpret_cast<const float4*>(chunkst + recbase + (size_t)j*768);
    *reinterpret_cast<float4*>(&rec[0]) = q[0];
    *reinterpret_cast<float4*>(&rec[4]) = q[1];
    *reinterpret_cast<float4*>(&rec[8]) = q[2];
    float ds = rec[11];
    if (fast){
      float r = __expf(aAll[0]*ds);
      float dA = 1.f;
      #pragma unroll
      for (int n=0;n<NS;n++){
        dA *= r;
        Bb[n] = fmaf(dA, Bb[n], rec[n]);
        Aa[n] *= dA;
      }
    } else {
      #pragma unroll
      for (int n=0;n<NS;n++){
        float dA = __expf(aAll[n]*ds);
        Bb[n] = fmaf(dA, Bb[n], rec[n]);
        Aa[n] *= dA;
      }
    }
  }
  #pragma unroll
  for (int n=0;n<NS;n++){
    float A = Aa[n], Bv = Bb[n];
    #pragma unroll
    for (int off=1; off<64; off<<=1){
      float Ap=__shfl_up(A,off,64), Bp=__shfl_up(Bv,off,64);
      if (lane>=off){ Bv = fmaf(A,Bp,Bv); A*=Ap; }
    }
    float hs = __shfl_up(Bv,1,64);
    Bb[n] = (lane==0) ? 0.f : hs;
  }
  #pragma unroll
  for (int j=0;j<8;j++){
    float rec[12];
    const float4* q = reinterpret_cast<const float4*>(chunkst + recbase + (size_t)j*768);
    *reinterpret_cast<float4*>(&rec[0]) = q[0];
    *reinterpret_cast<float4*>(&rec[4]) = q[1];
    *reinterpret_cast<float4*>(&rec[8]) = q[2];
    float ds = rec[11];
    float outv[12];
    if (fast){
      float r = __expf(aAll[0]*ds);
      float dA = 1.f;
      #pragma unroll
      for (int n=0;n<NS;n++){
        outv[n] = Bb[n];
        dA *= r;
        Bb[n] = fmaf(dA, Bb[n], rec[n]);
      }
    } else {
      #pragma unroll
      for (int n=0;n<NS;n++){
        outv[n] = Bb[n];
        float dA = __expf(aAll[n]*ds);
        Bb[n] = fmaf(dA, Bb[n], rec[n]);
      }
    }
    outv[11] = 0.f;
    float4* o = reinterpret_cast<float4*>(hin + recbase + (size_t)j*768);
    o[0] = *reinterpret_cast<float4*>(&outv[0]);
    o[1] = *reinterpret_cast<float4*>(&outv[4]);
    o[2] = *reinterpret_cast<float4*>(&outv[8]);
  }
}

// ---------------- K5: replay scan with h_in, y, RMSNorm over D, SiLU gating -------
__global__ __launch_bounds__(256,4) void k_scanB(const __half2* __restrict__ duo,
                                               const __half* __restrict__ bch,
                                               const float* __restrict__ Alog,
                                               const float* __restrict__ hin,
                                               const float* __restrict__ Dsv,
                                               const float* __restrict__ rmss,
                                               const float* __restrict__ x,
                                               float* __restrict__ out){
  const int task = blockIdx.x*4 + (threadIdx.x>>6);
  const int d = threadIdx.x & 63;
  const int b = task / NC, c = task % NC;
  float a0 = -expf(Alog[d*NS]);
  bool fast = true;
  #pragma unroll
  for (int n=1;n<NS;n++){
    float an = -expf(Alog[d*NS+n]);
    fast = fast && (fabsf(an - (float)(n+1)*a0) <= 1e-4f*(float)(n+1));
  }
  float h[12];
  {
    const float4* q = reinterpret_cast<const float4*>(hin + ((size_t)task*64 + d)*12);
    *reinterpret_cast<float4*>(&h[0]) = q[0];
    *reinterpret_cast<float4*>(&h[4]) = q[1];
    *reinterpret_cast<float4*>(&h[8]) = q[2];
  }
  const float Dd = Dsv[d];
  const float rsc = rmss[d];
  const int l0 = c*LC;
  #pragma unroll 2
  for (int l=l0; l<l0+LC; ++l){
    size_t p = (size_t)b*LL + l;
    __half2 dv = duo[p*DD+d];
    float de = __low2float(dv), uu = __high2float(dv);
    float du = de*uu;
    __half2 h2[12];
    {
      const float4* q = reinterpret_cast<const float4*>(bch + p*24);
      *reinterpret_cast<float4*>(&h2[0]) = q[0];
      *reinterpret_cast<float4*>(&h2[4]) = q[1];
      *reinterpret_cast<float4*>(&h2[8]) = q[2];
    }
    float y = Dd*uu;
    if (fast){
      float r = __expf(a0*de);
      float dA = 1.f;
      #pragma unroll
      for (int n=0;n<NS;n++){
        dA *= r;
        float bn = (n&1) ? __high2float(h2[n>>1]) : __low2float(h2[n>>1]);
        float cn = (n&1) ? __high2float(h2[(12+n)>>1]) : __low2float(h2[(12+n)>>1]);
        h[n] = fmaf(dA, h[n], du*bn);
        y = fmaf(h[n], cn, y);
      }
    } else {
      #pragma unroll
      for (int n=0;n<NS;n++){
        float dA = __expf(-expf(Alog[d*NS+n])*de);
        float bn = (n&1) ? __high2float(h2[n>>1]) : __low2float(h2[n>>1]);
        float cn = (n&1) ? __high2float(h2[(12+n)>>1]) : __low2float(h2[(12+n)>>1]);
        h[n] = fmaf(dA, h[n], du*bn);
        y = fmaf(h[n], cn, y);
      }
    }
    float ss = y*y;
    #pragma unroll
    for (int m=1;m<64;m<<=1) ss += __shfl_xor(ss, m, 64);
    float yn = rsc * rsqrtf(ss*(1.f/64.f) + 1e-5f) * y;
    float z = x[p*DD+d];
    out[p*DD+d] = yn * (z * sigmoidf_(z));
  }
}

extern "C" void kernel_launch(void* const* d_in, const int* in_sizes, int n_in,
                              void* d_out, int out_size, void* d_ws, size_t ws_size,
                              hipStream_t stream) {
  const float* x     = (const float*)d_in[0];
  const float* w     = (const float*)d_in[1];
  const float* gamma = (const float*)d_in[2];
  const float* beta  = (const float*)d_in[3];
  const float* xpw   = (const float*)d_in[4];
  const float* dtw   = (const float*)d_in[5];
  const float* dtb   = (const float*)d_in[6];
  const float* Alog  = (const float*)d_in[7];
  const float* Dsv   = (const float*)d_in[8];
  const float* rmss  = (const float*)d_in[9];
  float* out = (float*)d_out;

  float* f = (float*)d_ws;
  const size_t n_xld = (size_t)NB*LL*DD;       // 4,194,304
  __half*  xc  = (__half*)f;                   // conv out (fp16, uses half of region)
  __half2* duo = (__half2*)(f + n_xld);        // (b,l,d): half2(de,u)
  __half*  bch = (__half*)(f + n_xld + 2*n_xld); // (b,l,24) fp16
  float* chunkst = f + n_xld + 2*n_xld + (size_t)NB*LL*24;
  float* hin     = chunkst + (size_t)NB*NC*64*12;
  float* bn_acc  = hin + (size_t)NB*NC*64*12;      // 64 buckets x 128

  k_zero   <<<NBKT*128/256, 256, 0, stream>>>(bn_acc);
  k_conv   <<<NB*(LL/CONV_LT), 512, 0, stream>>>(x, w, xc, bn_acc);
  k_proj   <<<NB*(LL/PJ), 256, 0, stream>>>(xc, bn_acc, gamma, beta, xpw, dtw, dtb, Alog, duo, bch, chunkst);
  k_scanMid<<<NB*DD, 64, 0, stream>>>(chunkst, Alog, hin);
  k_scanB  <<<(NB*NC)/4, 256, 0, stream>>>(duo, bch, Alog, hin, Dsv, rmss, x, out);
}

// Round 19
// 83.490 us; speedup vs baseline: 1.4191x; 1.0677x over previous
//
#include <hip/hip_runtime.h>
#include <hip/hip_bf16.h>
#include <hip/hip_fp16.h>
#include <math.h>

#define NB 8
#define LL 8192
#define DD 64
#define NS 11
#define NR 4
#define NC 512        // chunks
#define LC (LL/NC)    // 16 positions per chunk
#define CONV_LT 128
#define KW 63
#define PJ 64         // proj tile = 4 chunks
#define NBKT 64       // BN atomic buckets
#define US 68         // LDS row stride for ul
#define WS 72         // LDS row stride for wsh2

__device__ __forceinline__ float sigmoidf_(float v){ return 1.f/(1.f+__expf(-v)); }
__device__ __forceinline__ float rnd16(float v){ return __half2float(__float2half_rn(v)); }

// ---------------- K0: zero the BN accumulator ----------------
__global__ void k_zero(float* __restrict__ p){
  p[blockIdx.x*256 + threadIdx.x] = 0.f;
}

// ---------------- K1: depthwise conv (k=63, pad 31) + bucketed BN partial sums ------
__global__ __launch_bounds__(512,4) void k_conv(const float* __restrict__ x,
                                              const float* __restrict__ w,
                                              __half* __restrict__ xc,
                                              float* __restrict__ bn_acc){
  const int b  = blockIdx.x / (LL/CONV_LT);
  const int lt = blockIdx.x % (LL/CONV_LT);
  const int l0 = lt*CONV_LT;
  __shared__ float xt[(CONV_LT+62)*DD];   // 47.5 KB
  __shared__ float rs[512], rq[512];
  const int t = threadIdx.x;
  for (int i=t; i<(CONV_LT+62)*DD; i+=512){
    int lrel = i/DD, d = i%DD;
    int lg = l0 - 31 + lrel;
    xt[i] = (lg>=0 && lg<LL) ? x[((size_t)b*LL+lg)*DD + d] : 0.f;
  }
  __syncthreads();
  const int d = t & 63;
  const int base = (t >> 6) * 16;       // 8 waves x 16 positions
  float acc[16];
  #pragma unroll
  for (int j=0;j<16;j++) acc[j]=0.f;
  #pragma unroll 1
  for (int kb=0; kb<4; ++kb){
    float wv[16];
    #pragma unroll
    for (int kk=0;kk<16;kk++){
      int k = kb*16+kk;
      wv[kk] = (k<KW) ? w[d*KW+k] : 0.f;
    }
    float xw[31];
    #pragma unroll
    for (int i=0;i<31;i++) xw[i] = xt[(base+kb*16+i)*DD + d];
    #pragma unroll
    for (int j=0;j<16;j++){
      #pragma unroll
      for (int kk=0;kk<16;kk++){
        acc[j] = fmaf(wv[kk], xw[j+kk], acc[j]);
      }
    }
  }
  float lsum=0.f, lsq=0.f;
  #pragma unroll
  for (int j=0;j<16;j++){
    xc[((size_t)b*LL + l0+base+j)*DD + d] = __float2half_rn(acc[j]);
    lsum += acc[j]; lsq = fmaf(acc[j],acc[j],lsq);
  }
  rs[t]=lsum; rq[t]=lsq;
  __syncthreads();
  if (t<64){
    float s=0.f, q=0.f;
    #pragma unroll
    for (int g=0; g<8; ++g){ s += rs[t+64*g]; q += rq[t+64*g]; }
    const int bkt = (blockIdx.x & (NBKT-1))*128;
    atomicAdd(&bn_acc[bkt+t],    s);
    atomicAdd(&bn_acc[bkt+64+t], q);
  }
}

// ---------------- K2: BN+SiLU ; x_proj ; merged dt-proj + chunk-local scan ----------
__global__ __launch_bounds__(256,4) void k_proj(const __half* __restrict__ xc,
                                              const float* __restrict__ bn_acc,
                                              const float* __restrict__ gamma,
                                              const float* __restrict__ beta,
                                              const float* __restrict__ xpw,
                                              const float* __restrict__ dtw,
                                              const float* __restrict__ dtb,
                                              const float* __restrict__ Alog,
                                              __half2* __restrict__ duo,
                                              __half* __restrict__ bch,
                                              float* __restrict__ chunkst){
  const int b  = blockIdx.x / (LL/PJ);
  const int lt = blockIdx.x % (LL/PJ);
  const int l0 = lt*PJ;
  __shared__ float ul[PJ*US];          // 17.4 KB
  __shared__ float bcl[PJ][24];        // 6 KB
  __shared__ float wsh2[26*WS];        // 7.3 KB
  __shared__ float xd[PJ*NR];          // 1 KB
  __shared__ float dtwsh[64*NR];       // 1 KB
  __shared__ float bnred[2][4][64];    // 2 KB
  const int t = threadIdx.x;
  for (int i=t; i<26*64; i+=256){ int c=i>>6, dd=i&63; wsh2[c*WS+dd] = xpw[i]; }
  dtwsh[t] = dtw[t];
  const int d = t & 63, wv = t >> 6;
  {
    float ms=0.f, qs=0.f;
    #pragma unroll
    for (int k=wv*16; k<wv*16+16; ++k){
      ms += bn_acc[k*128 + d];
      qs += bn_acc[k*128 + 64 + d];
    }
    bnred[0][wv][d]=ms; bnred[1][wv][d]=qs;
  }
  __syncthreads();
  float msum = bnred[0][0][d]+bnred[0][1][d]+bnred[0][2][d]+bnred[0][3][d];
  float qsum = bnred[1][0][d]+bnred[1][1][d]+bnred[1][2][d]+bnred[1][3][d];
  const float inv_n = 1.f/((float)NB*(float)LL);
  float mean = msum*inv_n;
  float var  = qsum*inv_n - mean*mean;
  float sc = gamma[d] * rsqrtf(var + 1e-5f);
  float sh = beta[d] - mean*sc;
  float uu[16];
  #pragma unroll
  for (int j=0;j<16;j++){
    int lr = wv*16 + j;
    float v = __half2float(xc[((size_t)b*LL + l0+lr)*DD + d]);
    v = fmaf(v, sc, sh);
    float u_ = rnd16(v * sigmoidf_(v));     // fp16-consistent with scanB
    uu[j] = u_;
    ul[lr*US+d] = u_;
  }
  __syncthreads();
  // x_proj matvec: 2 cols x 4 pos x 4-dd float4 blocking
  {
    const int cp  = t & 15;
    const int lrb = t >> 4;
    if (cp < 13){
      float acc0[4] = {0.f,0.f,0.f,0.f};
      float acc1[4] = {0.f,0.f,0.f,0.f};
      #pragma unroll 2
      for (int dd4=0; dd4<16; ++dd4){
        float4 w0 = *reinterpret_cast<const float4*>(&wsh2[(2*cp  )*WS + dd4*4]);
        float4 w1 = *reinterpret_cast<const float4*>(&wsh2[(2*cp+1)*WS + dd4*4]);
        #pragma unroll
        for (int p=0;p<4;p++){
          float4 uv = *reinterpret_cast<const float4*>(&ul[(lrb*4+p)*US + dd4*4]);
          acc0[p] = fmaf(w0.x,uv.x, fmaf(w0.y,uv.y, fmaf(w0.z,uv.z, fmaf(w0.w,uv.w, acc0[p]))));
          acc1[p] = fmaf(w1.x,uv.x, fmaf(w1.y,uv.y, fmaf(w1.z,uv.z, fmaf(w1.w,uv.w, acc1[p]))));
        }
      }
      #pragma unroll
      for (int cc=0; cc<2; ++cc){
        int c = 2*cp+cc;
        #pragma unroll
        for (int p=0;p<4;p++){
          int lr = lrb*4+p;
          float v = cc ? acc1[p] : acc0[p];
          if (c < NR) xd[lr*NR+c] = v;
          else {
            int pos = c - NR;                       // B:0..10  C:11..21
            int slot = (pos < NS) ? pos : pos+1;    // pad slots 11 and 23
            float vr = rnd16(v);                    // fp16-consistent
            bcl[lr][slot] = vr;
            bch[((size_t)b*LL + l0+lr)*24 + slot] = __float2half_rn(v);
          }
        }
      }
    }
  }
  __syncthreads();
  // merged dt-proj + softplus + duo(half2) store + chunk-local scan
  {
    const float bias = dtb[d];
    const float dw0 = dtwsh[d*NR+0], dw1 = dtwsh[d*NR+1],
                dw2 = dtwsh[d*NR+2], dw3 = dtwsh[d*NR+3];
    float a0 = -__expf(Alog[d*NS]);
    bool fast = true;
    #pragma unroll
    for (int n=1;n<NS;n++){
      float an = -__expf(Alog[d*NS+n]);
      fast = fast && (fabsf(an - (float)(n+1)*a0) <= 1e-4f*(float)(n+1));
    }
    const int task = b*NC + lt*4 + wv;
    float h[12];
    #pragma unroll
    for (int n=0;n<12;n++) h[n]=0.f;
    float dsum=0.f;
    #pragma unroll 4
    for (int l=0;l<LC;++l){
      int lr = wv*LC + l;
      float4 xv = *reinterpret_cast<const float4*>(&xd[lr*NR]);
      float s = fmaf(dw0,xv.x, fmaf(dw1,xv.y, fmaf(dw2,xv.z, fmaf(dw3,xv.w, bias))));
      float de = rnd16(fmaxf(s,0.f) + __logf(1.f + __expf(-fabsf(s))));
      float u_ = uu[l];
      float du = de*u_;
      dsum += de;
      duo[((size_t)b*LL + l0+lr)*DD + d] = __floats2half2_rn(de, u_);
      float bca[12];
      const float4* q = reinterpret_cast<const float4*>(&bcl[lr][0]);
      *reinterpret_cast<float4*>(&bca[0]) = q[0];
      *reinterpret_cast<float4*>(&bca[4]) = q[1];
      *reinterpret_cast<float4*>(&bca[8]) = q[2];
      if (fast){
        float r = __expf(a0*de);
        float dA = 1.f;
        #pragma unroll
        for (int n=0;n<NS;n++){
          dA *= r;
          h[n] = fmaf(dA, h[n], du*bca[n]);
        }
      } else {
        #pragma unroll
        for (int n=0;n<NS;n++){
          float dA = __expf(-__expf(Alog[d*NS+n])*de);
          h[n] = fmaf(dA, h[n], du*bca[n]);
        }
      }
    }
    h[11] = dsum;
    float4* o = reinterpret_cast<float4*>(chunkst + ((size_t)task*64 + d)*12);
    o[0] = *reinterpret_cast<float4*>(&h[0]);
    o[1] = *reinterpret_cast<float4*>(&h[4]);
    o[2] = *reinterpret_cast<float4*>(&h[8]);
  }
}

// ---------------- K4: cross-chunk propagation — one wave per (b,d), recs in regs ----
__global__ __launch_bounds__(64) void k_scanMid(const float* __restrict__ chunkst,
                                                const float* __restrict__ Alog,
                                                float* __restrict__ hin){
  const int wid  = blockIdx.x;
  const int lane = threadIdx.x & 63;
  const int b = wid >> 6, d = wid & 63;
  const int c0 = lane*8;
  const size_t recbase = (((size_t)b*NC + c0)*64 + d)*12;
  // load all 8 records into registers once (96 VGPR; 1-wave block => ample budget)
  float rec[8][12];
  #pragma unroll
  for (int j=0;j<8;j++){
    const float4* q = reinterpret_cast<const float4*>(chunkst + recbase + (size_t)j*768);
    *reinterpret_cast<float4*>(&rec[j][0]) = q[0];
    *reinterpret_cast<float4*>(&rec[j][4]) = q[1];
    *reinterpret_cast<float4*>(&rec[j][8]) = q[2];
  }
  float aAll[NS];
  #pragma unroll
  for (int n=0;n<NS;n++) aAll[n] = -expf(Alog[d*NS+n]);
  bool fast = true;
  #pragma unroll
  for (int n=1;n<NS;n++)
    fast = fast && (fabsf(aAll[n] - (float)(n+1)*aAll[0]) <= 1e-4f*(float)(n+1));
  float Aa[NS], Bb[NS];
  #pragma unroll
  for (int n=0;n<NS;n++){ Aa[n]=1.f; Bb[n]=0.f; }
  #pragma unroll
  for (int j=0;j<8;j++){
    float ds = rec[j][11];
    if (fast){
      float r = __expf(aAll[0]*ds);
      float dA = 1.f;
      #pragma unroll
      for (int n=0;n<NS;n++){
        dA *= r;
        Bb[n] = fmaf(dA, Bb[n], rec[j][n]);
        Aa[n] *= dA;
      }
    } else {
      #pragma unroll
      for (int n=0;n<NS;n++){
        float dA = __expf(aAll[n]*ds);
        Bb[n] = fmaf(dA, Bb[n], rec[j][n]);
        Aa[n] *= dA;
      }
    }
  }
  #pragma unroll
  for (int n=0;n<NS;n++){
    float A = Aa[n], Bv = Bb[n];
    #pragma unroll
    for (int off=1; off<64; off<<=1){
      float Ap=__shfl_up(A,off,64), Bp=__shfl_up(Bv,off,64);
      if (lane>=off){ Bv = fmaf(A,Bp,Bv); A*=Ap; }
    }
    float hs = __shfl_up(Bv,1,64);
    Bb[n] = (lane==0) ? 0.f : hs;
  }
  #pragma unroll
  for (int j=0;j<8;j++){
    float ds = rec[j][11];
    float outv[12];
    if (fast){
      float r = __expf(aAll[0]*ds);
      float dA = 1.f;
      #pragma unroll
      for (int n=0;n<NS;n++){
        outv[n] = Bb[n];
        dA *= r;
        Bb[n] = fmaf(dA, Bb[n], rec[j][n]);
      }
    } else {
      #pragma unroll
      for (int n=0;n<NS;n++){
        outv[n] = Bb[n];
        float dA = __expf(aAll[n]*ds);
        Bb[n] = fmaf(dA, Bb[n], rec[j][n]);
      }
    }
    outv[11] = 0.f;
    float4* o = reinterpret_cast<float4*>(hin + recbase + (size_t)j*768);
    o[0] = *reinterpret_cast<float4*>(&outv[0]);
    o[1] = *reinterpret_cast<float4*>(&outv[4]);
    o[2] = *reinterpret_cast<float4*>(&outv[8]);
  }
}

// ---------------- K5: replay scan, 4-position load tiling, RMSNorm, SiLU gate ------
__global__ __launch_bounds__(256,4) void k_scanB(const __half2* __restrict__ duo,
                                               const __half* __restrict__ bch,
                                               const float* __restrict__ Alog,
                                               const float* __restrict__ hin,
                                               const float* __restrict__ Dsv,
                                               const float* __restrict__ rmss,
                                               const float* __restrict__ x,
                                               float* __restrict__ out){
  const int task = blockIdx.x*4 + (threadIdx.x>>6);
  const int d = threadIdx.x & 63;
  const int b = task / NC, c = task % NC;
  float a0 = -expf(Alog[d*NS]);
  bool fast = true;
  #pragma unroll
  for (int n=1;n<NS;n++){
    float an = -expf(Alog[d*NS+n]);
    fast = fast && (fabsf(an - (float)(n+1)*a0) <= 1e-4f*(float)(n+1));
  }
  float h[12];
  {
    const float4* q = reinterpret_cast<const float4*>(hin + ((size_t)task*64 + d)*12);
    *reinterpret_cast<float4*>(&h[0]) = q[0];
    *reinterpret_cast<float4*>(&h[4]) = q[1];
    *reinterpret_cast<float4*>(&h[8]) = q[2];
  }
  const float Dd = Dsv[d];
  const float rsc = rmss[d];
  const int l0 = c*LC;
  #pragma unroll 1
  for (int g=0; g<LC/4; ++g){
    // batched loads: 4 positions' duo + bch (all independent of the h-chain)
    __half2 dv[4];
    float4 bq0[4], bq1[4], bq2[4];
    float xz[4];
    #pragma unroll
    for (int i=0;i<4;i++){
      size_t p = (size_t)b*LL + l0 + g*4 + i;
      dv[i] = duo[p*DD+d];
      const float4* q = reinterpret_cast<const float4*>(bch + p*24);
      bq0[i]=q[0]; bq1[i]=q[1]; bq2[i]=q[2];
      xz[i] = x[p*DD+d];
    }
    #pragma unroll
    for (int i=0;i<4;i++){
      size_t p = (size_t)b*LL + l0 + g*4 + i;
      float de = __low2float(dv[i]), uu = __high2float(dv[i]);
      float du = de*uu;
      __half2 h2[12];
      *reinterpret_cast<float4*>(&h2[0]) = bq0[i];
      *reinterpret_cast<float4*>(&h2[4]) = bq1[i];
      *reinterpret_cast<float4*>(&h2[8]) = bq2[i];
      float y = Dd*uu;
      if (fast){
        float r = __expf(a0*de);
        float dA = 1.f;
        #pragma unroll
        for (int n=0;n<NS;n++){
          dA *= r;
          float bn = (n&1) ? __high2float(h2[n>>1]) : __low2float(h2[n>>1]);
          float cn = (n&1) ? __high2float(h2[(12+n)>>1]) : __low2float(h2[(12+n)>>1]);
          h[n] = fmaf(dA, h[n], du*bn);
          y = fmaf(h[n], cn, y);
        }
      } else {
        #pragma unroll
        for (int n=0;n<NS;n++){
          float dA = __expf(-expf(Alog[d*NS+n])*de);
          float bn = (n&1) ? __high2float(h2[n>>1]) : __low2float(h2[n>>1]);
          float cn = (n&1) ? __high2float(h2[(12+n)>>1]) : __low2float(h2[(12+n)>>1]);
          h[n] = fmaf(dA, h[n], du*bn);
          y = fmaf(h[n], cn, y);
        }
      }
      float ss = y*y;
      #pragma unroll
      for (int m=1;m<64;m<<=1) ss += __shfl_xor(ss, m, 64);
      float yn = rsc * rsqrtf(ss*(1.f/64.f) + 1e-5f) * y;
      float z = xz[i];
      out[p*DD+d] = yn * (z * sigmoidf_(z));
    }
  }
}

extern "C" void kernel_launch(void* const* d_in, const int* in_sizes, int n_in,
                              void* d_out, int out_size, void* d_ws, size_t ws_size,
                              hipStream_t stream) {
  const float* x     = (const float*)d_in[0];
  const float* w     = (const float*)d_in[1];
  const float* gamma = (const float*)d_in[2];
  const float* beta  = (const float*)d_in[3];
  const float* xpw   = (const float*)d_in[4];
  const float* dtw   = (const float*)d_in[5];
  const float* dtb   = (const float*)d_in[6];
  const float* Alog  = (const float*)d_in[7];
  const float* Dsv   = (const float*)d_in[8];
  const float* rmss  = (const float*)d_in[9];
  float* out = (float*)d_out;

  float* f = (float*)d_ws;
  const size_t n_xld = (size_t)NB*LL*DD;       // 4,194,304
  __half*  xc  = (__half*)f;                   // conv out (fp16)
  __half2* duo = (__half2*)(f + n_xld);        // (b,l,d): half2(de,u)
  __half*  bch = (__half*)(f + n_xld + 2*n_xld); // (b,l,24) fp16
  float* chunkst = f + n_xld + 2*n_xld + (size_t)NB*LL*24;
  float* hin     = chunkst + (size_t)NB*NC*64*12;
  float* bn_acc  = hin + (size_t)NB*NC*64*12;      // 64 buckets x 128

  k_zero   <<<NBKT*128/256, 256, 0, stream>>>(bn_acc);
  k_conv   <<<NB*(LL/CONV_LT), 512, 0, stream>>>(x, w, xc, bn_acc);
  k_proj   <<<NB*(LL/PJ), 256, 0, stream>>>(xc, bn_acc, gamma, beta, xpw, dtw, dtb, Alog, duo, bch, chunkst);
  k_scanMid<<<NB*DD, 64, 0, stream>>>(chunkst, Alog, hin);
  k_scanB  <<<(NB*NC)/4, 256, 0, stream>>>(duo, bch, Alog, hin, Dsv, rmss, x, out);
}